// Round 9
// baseline (1332.597 us; speedup 1.0000x reference)
//
#include <hip/hip_runtime.h>

typedef float f32x2 __attribute__((ext_vector_type(2)));

namespace {
constexpr int T_STEPS = 512;
constexpr int BATCH   = 8;
constexpr int NH      = 16;   // nheads
constexpr int HD      = 64;   // headdim
constexpr int DS      = 64;   // d_state
constexpr int DI      = 1024; // d_inner
constexpr long H_TSTRIDE = (long)BATCH * NH * HD * DS; // 524288 floats per timestep of H
constexpr int PF      = 4;    // prefetch pipeline depth (divides T_STEPS)
}

// One block = (b, h, group of 8 p's). Each wave handles 2 p's, 32 lanes per p,
// each lane holds an f32x2 of n (d_state) in registers -> 262144 threads,
// 1024 blocks, 16 waves/CU (4/SIMD) for latency hiding on the sequential scan.
// H trajectory streamed out with nontemporal stores (512 B contiguous/wave;
// 2 KB contiguous per block per timestep). Per-timestep operands
// (x, B, C, decay, z) are software-pipelined to depth PF=4 with statically-
// indexed rotating buffers (inner loop fully unrolled so all buffer indices
// are compile-time — no scratch). The decay sigmoid is evaluated at PREFETCH
// time (off the carried chain), so the loop-carried H chain is a single FMA.
// The last PF timesteps are peeled into an epilogue so the steady-state loop
// body is branch-free.
__global__ __launch_bounds__(256) void mamba2_scan_kernel(
    const float* __restrict__ x,      // [T,B,1024]
    const float* __restrict__ Bp,     // [T,B,64]
    const float* __restrict__ Cp,     // [T,B,64]
    const float* __restrict__ dt,     // [T,B,16]
    const float* __restrict__ z,      // [T,B,1024]
    const float* __restrict__ H0,     // [B,16,64,64]
    const float* __restrict__ dt_bias,// [16]
    float* __restrict__ out,          // [T,B,1024]
    float* __restrict__ H)            // [T+1,B,16,64,64]
{
    const int tid     = threadIdx.x;
    const int wave    = tid >> 6;
    const int lane    = tid & 63;
    const int p_local = lane >> 5;     // 0..1 within wave
    const int nq      = lane & 31;     // 32 lanes per p
    const int n0      = nq << 1;       // f32x2 chunk of n

    const int blk = blockIdx.x;        // b*128 + h*8 + pg
    const int pg  = blk & 7;
    const int h   = (blk >> 3) & 15;
    const int b   = blk >> 7;
    const int p   = pg * 8 + wave * 2 + p_local;   // 0..63

    const float bias = dt_bias[h];

    // state load (H0 has same [b,h,p,n] layout as one timestep of H)
    const long hbase = ((long)((b * NH + h) * HD + p)) * DS + n0;
    f32x2 Hreg = *reinterpret_cast<const f32x2*>(H0 + hbase);

    // H[0] = H0
    __builtin_nontemporal_store(Hreg, reinterpret_cast<f32x2*>(H + hbase));

    const long x_idx  = (long)b * DI + h * HD + p;
    const long bc_idx = (long)b * DS + n0;
    const long dt_idx = (long)b * NH + h;

    const float* xp  = x  + x_idx;
    const float* bpp = Bp + bc_idx;
    const float* cpp = Cp + bc_idx;
    const float* dtp = dt + dt_idx;
    const float* zp  = z  + x_idx;     // same layout/index as x
    float*       op  = out + x_idx;
    float*       hp  = H + hbase + H_TSTRIDE;   // H[1]

    const bool writer = (nq == 0);

    // rotating operand buffers, always statically indexed
    float xb[PF], db[PF], zb[PF];
    f32x2 Bb[PF], Cb[PF];

    // prime stages 0..PF-1 (t = 0..PF-1); T_STEPS >= 2*PF
#pragma unroll
    for (int s = 0; s < PF; ++s) {
        xb[s] = xp [(long)s * (BATCH * DI)];
        Bb[s] = *reinterpret_cast<const f32x2*>(bpp + (long)s * (BATCH * DS));
        Cb[s] = *reinterpret_cast<const f32x2*>(cpp + (long)s * (BATCH * DS));
        const float dtv = dtp[(long)s * (BATCH * NH)];
        db[s] = 1.0f / (1.0f + expf(-(dtv + bias)));   // sigmoid, off critical path
        zb[s] = zp [(long)s * (BATCH * DI)];
    }

    // steady state: t in [0, T_STEPS-PF), prefetch always in-bounds
    for (int tt = 0; tt < T_STEPS - PF; tt += PF) {
#pragma unroll
        for (int s = 0; s < PF; ++s) {
            const float xv = xb[s];
            const f32x2 Bv = Bb[s];
            const f32x2 Cv = Cb[s];
            const float d  = db[s];
            const float zv = zb[s];

            // unconditional prefetch of t+PF into slot s
            xb[s] = xp [(long)(s + PF) * (BATCH * DI)];
            Bb[s] = *reinterpret_cast<const f32x2*>(bpp + (long)(s + PF) * (BATCH * DS));
            Cb[s] = *reinterpret_cast<const f32x2*>(cpp + (long)(s + PF) * (BATCH * DS));
            const float dtv = dtp[(long)(s + PF) * (BATCH * NH)];
            db[s] = 1.0f / (1.0f + expf(-(dtv + bias)));
            zb[s] = zp [(long)(s + PF) * (BATCH * DI)];

            // H = d*H + x[p] * B[n]   (the only loop-carried chain: 1 FMA)
            Hreg.x = fmaf(d, Hreg.x, xv * Bv.x);
            Hreg.y = fmaf(d, Hreg.y, xv * Bv.y);

            // stream state out (512 B contiguous per wave)
            __builtin_nontemporal_store(Hreg,
                reinterpret_cast<f32x2*>(hp + (long)s * H_TSTRIDE));

            // y[p] = sum_n H[p][n] * C[n]
            float part = Hreg.x * Cv.x + Hreg.y * Cv.y;
            part += __shfl_xor(part,  1, 32);
            part += __shfl_xor(part,  2, 32);
            part += __shfl_xor(part,  4, 32);
            part += __shfl_xor(part,  8, 32);
            part += __shfl_xor(part, 16, 32);

            if (writer) {
                const float sgz = zv + part;             // z + y
                const float sig = 1.0f / (1.0f + expf(-sgz));
                __builtin_nontemporal_store(part * (sgz * sig),
                                            op + (long)s * (BATCH * DI));
            }
        }

        xp  += (long)PF * (BATCH * DI);
        bpp += (long)PF * (BATCH * DS);
        cpp += (long)PF * (BATCH * DS);
        dtp += (long)PF * (BATCH * NH);
        zp  += (long)PF * (BATCH * DI);
        op  += (long)PF * (BATCH * DI);
        hp  += (long)PF * H_TSTRIDE;
    }

    // epilogue: last PF timesteps, consume buffers, no prefetch
#pragma unroll
    for (int s = 0; s < PF; ++s) {
        const float xv = xb[s];
        const f32x2 Bv = Bb[s];
        const f32x2 Cv = Cb[s];
        const float d  = db[s];
        const float zv = zb[s];

        Hreg.x = fmaf(d, Hreg.x, xv * Bv.x);
        Hreg.y = fmaf(d, Hreg.y, xv * Bv.y);

        __builtin_nontemporal_store(Hreg,
            reinterpret_cast<f32x2*>(hp + (long)s * H_TSTRIDE));

        float part = Hreg.x * Cv.x + Hreg.y * Cv.y;
        part += __shfl_xor(part,  1, 32);
        part += __shfl_xor(part,  2, 32);
        part += __shfl_xor(part,  4, 32);
        part += __shfl_xor(part,  8, 32);
        part += __shfl_xor(part, 16, 32);

        if (writer) {
            const float sgz = zv + part;
            const float sig = 1.0f / (1.0f + expf(-sgz));
            __builtin_nontemporal_store(part * (sgz * sig),
                                        op + (long)s * (BATCH * DI));
        }
    }
}

extern "C" void kernel_launch(void* const* d_in, const int* in_sizes, int n_in,
                              void* d_out, int out_size, void* d_ws, size_t ws_size,
                              hipStream_t stream) {
    const float* x  = (const float*)d_in[0];
    const float* Bp = (const float*)d_in[1];
    const float* Cp = (const float*)d_in[2];
    const float* dt = (const float*)d_in[3];
    const float* z  = (const float*)d_in[4];
    const float* H0 = (const float*)d_in[5];
    const float* db = (const float*)d_in[6];

    float* out = (float*)d_out;
    float* H   = (float*)d_out + (long)T_STEPS * BATCH * DI; // output first, then H

    dim3 grid(BATCH * NH * (HD / 8));    // 1024 blocks
    dim3 block(256);
    hipLaunchKernelGGL(mamba2_scan_kernel, grid, block, 0, stream,
                       x, Bp, Cp, dt, z, H0, db, out, H);
}